// Round 9
// baseline (880.561 us; speedup 1.0000x reference)
//
#include <hip/hip_runtime.h>
#include <stdint.h>
#include <stddef.h>

typedef __bf16 bf16_t;
typedef __bf16 bf16x8 __attribute__((ext_vector_type(8)));
typedef __bf16 bf16x4 __attribute__((ext_vector_type(4)));
typedef float  f32x4  __attribute__((ext_vector_type(4)));

// ---------------------------------------------------------------------------
// Kernel 1: per-block partial sums of |W|  (W is 1024x1024 fp32)
// ---------------------------------------------------------------------------
__global__ __launch_bounds__(256)
void k_abssum(const float* __restrict__ W, float* __restrict__ partials) {
    const int t = threadIdx.x;
    const int b = blockIdx.x;
    const f32x4* W4 = reinterpret_cast<const f32x4*>(W);
    float s = 0.f;
    const int base = b * 1024 + t;           // float4 index
#pragma unroll
    for (int i = 0; i < 4; ++i) {
        f32x4 v = W4[base + i * 256];
        s += fabsf(v[0]) + fabsf(v[1]) + fabsf(v[2]) + fabsf(v[3]);
    }
#pragma unroll
    for (int off = 32; off > 0; off >>= 1) s += __shfl_down(s, off);
    __shared__ float red[4];
    if ((t & 63) == 0) red[t >> 6] = s;
    __syncthreads();
    if (t == 0) partials[b] = red[0] + red[1] + red[2] + red[3];
}

// ---------------------------------------------------------------------------
// Kernel 2: combine partials -> scale; ternarize W into fragment-tiled layout:
//   T[bn(8)][kt(16)][kq8(8)][nn(128)][8 bf16]   (2 MB total)
// GEMM's global_load_lds is a linear 16 KB tile copy; b128 fragment reads are
// contiguous per quarter-wave.
// ---------------------------------------------------------------------------
__global__ __launch_bounds__(256)
void k_ternarize(const float* __restrict__ W, const float* __restrict__ partials,
                 bf16_t* __restrict__ T, float* __restrict__ scale_out) {
    const int t = threadIdx.x;
    float s = partials[t];
#pragma unroll
    for (int off = 32; off > 0; off >>= 1) s += __shfl_down(s, off);
    __shared__ float red[4];
    if ((t & 63) == 0) red[t >> 6] = s;
    __syncthreads();
    const float total = red[0] + red[1] + red[2] + red[3];
    const float scale = total * (1.0f / 1048576.0f);
    const float inv   = 1.0f / fmaxf(scale, 1e-8f);

    const int c  = blockIdx.x * 256 + t;     // chunk id, 131072 total
    const int n  = c >> 7;                   // 0..1023 (row of W)
    const int k  = (c & 127) * 8;            // 0..1016
    const float* wp = W + (size_t)n * 1024 + k;
    f32x4 w0 = *reinterpret_cast<const f32x4*>(wp);
    f32x4 w1 = *reinterpret_cast<const f32x4*>(wp + 4);
    bf16x8 q;
#pragma unroll
    for (int j = 0; j < 4; ++j) {
        float q0 = fminf(1.f, fmaxf(-1.f, rintf(w0[j] * inv)));
        float q1 = fminf(1.f, fmaxf(-1.f, rintf(w1[j] * inv)));
        q[j]     = (bf16_t)q0;
        q[4 + j] = (bf16_t)q1;
    }
    const int bn = n >> 7, nn = n & 127;
    const int kt = k >> 6, kq8 = (k & 63) >> 3;
    const size_t chunk = ((size_t)(bn * 16 + kt) * 8 + kq8) * 128 + nn;
    reinterpret_cast<bf16x8*>(T)[chunk] = q;
    if (c == 0) scale_out[0] = scale;
}

// ---------------------------------------------------------------------------
// Kernel 3: GEMM  out[m][n] = scale * sum_k x[m][k]*t[n][k] + bias[n]
// M=65536, N=1024, K=1024.  BM=BN=128, BK=64, 256 threads (4 waves, 2x2).
// A: NO LDS — fragments loaded straight from global per lane (16 rows x
//    128 B contiguous per wave per (mi,kk); each element once per block;
//    L2-served via XCD swizzle ~8x panel reuse), fused fp32->bf16 cvt.
// B: double-buffered LDS (2 x 16 KB), global_load_lds of pre-tiled fragments,
//    prefetch distance 1; ONE __syncthreads per tile (load latency covered
//    by the 32-MFMA compute phase before the barrier drain).
// ---------------------------------------------------------------------------
__global__ __launch_bounds__(256, 3)
void k_gemm(const float* __restrict__ X, const bf16_t* __restrict__ T,
            const float* __restrict__ bias, const float* __restrict__ scale_p,
            float* __restrict__ Out) {
    __shared__ bf16_t Bs[2][8192];   // [buf][kq8(8)][n(128)][8]

    const int tid  = threadIdx.x;
    const int lane = tid & 63;
    const int w    = tid >> 6;
    const int wr   = w >> 1;
    const int wc   = w & 1;
    const int lq   = lane >> 4;
    const int rl   = lane & 15;

    // XCD-aware bijective swizzle (4096 blocks, 8 XCDs): 8 consecutive sids
    // within an XCD share one A-panel.
    const int bid  = blockIdx.x;
    const int sid  = (bid & 7) * 512 + (bid >> 3);
    const int bn   = sid & 7;
    const int bm   = sid >> 3;
    const int row0 = bm * 128;
    const int col0 = bn * 128;

    // ---- B staging: 16 x 1 KB issues per tile; wave w does 4 (linear copy)
    const bf16_t* gB = T + (size_t)bn * 16 * 8192 + (size_t)(w * 4) * 512 + (size_t)lane * 8;
    const int ldsBoff = w * 4 * 512;   // element offset within a buffer

    // ---- A per-lane fragment base: row = row0 + wr*64 + rl, k = lq*8
    const float* xbase = X + (size_t)(row0 + wr * 64 + rl) * 1024 + lq * 8;

    // ---- B fragment read byte-offsets within a buffer (loop-invariant)
    int boff[2][4];
#pragma unroll
    for (int kk = 0; kk < 2; ++kk)
#pragma unroll
        for (int i = 0; i < 4; ++i)
            boff[kk][i] = ((kk * 4 + lq) * 128 + wc * 64 + i * 16 + rl) * 16;

    f32x4 acc[4][4];
    {
        f32x4 z = {0.f, 0.f, 0.f, 0.f};
#pragma unroll
        for (int i = 0; i < 4; ++i)
#pragma unroll
            for (int j = 0; j < 4; ++j) acc[i][j] = z;
    }

    // ---- prologue: stage B tile 0 into buffer 0
#pragma unroll
    for (int i = 0; i < 4; ++i)
        __builtin_amdgcn_global_load_lds(
            (const __attribute__((address_space(1))) void*)(gB + i * 512),
            (__attribute__((address_space(3))) void*)(&Bs[0][ldsBoff + i * 512]), 16, 0, 0);
    __syncthreads();

    for (int kt = 0; kt < 16; ++kt) {
        const int cur = kt & 1;
        // --- prefetch next B tile into the other buffer (drains at the
        //     barrier BELOW, after a full compute phase covers the latency)
        if (kt + 1 < 16) {
#pragma unroll
            for (int i = 0; i < 4; ++i)
                __builtin_amdgcn_global_load_lds(
                    (const __attribute__((address_space(1))) void*)(gB + (size_t)(kt + 1) * 8192 + i * 512),
                    (__attribute__((address_space(3))) void*)(&Bs[cur ^ 1][ldsBoff + i * 512]), 16, 0, 0);
        }
        const char* bbase = (const char*)&Bs[cur][0];
#pragma unroll
        for (int kk = 0; kk < 2; ++kk) {
            // A fragments straight from global (fp32), fused cvt to bf16
            f32x4 r0[4], r1[4];
#pragma unroll
            for (int mi = 0; mi < 4; ++mi) {
                const float* p = xbase + (size_t)mi * 16384 + kt * 64 + kk * 32;
                r0[mi] = *(const f32x4*)(p);
                r1[mi] = *(const f32x4*)(p + 4);
            }
            bf16x8 af[4], bfr[4];
#pragma unroll
            for (int mi = 0; mi < 4; ++mi)
#pragma unroll
                for (int j = 0; j < 4; ++j) {
                    af[mi][j]     = (bf16_t)r0[mi][j];
                    af[mi][4 + j] = (bf16_t)r1[mi][j];
                }
#pragma unroll
            for (int ni = 0; ni < 4; ++ni)
                bfr[ni] = *reinterpret_cast<const bf16x8*>(bbase + boff[kk][ni]);
#pragma unroll
            for (int mi = 0; mi < 4; ++mi)
#pragma unroll
                for (int ni = 0; ni < 4; ++ni)
                    acc[mi][ni] = __builtin_amdgcn_mfma_f32_16x16x32_bf16(
                        af[mi], bfr[ni], acc[mi][ni], 0, 0, 0);
        }
        __syncthreads();   // B[cur] reads done; B[cur^1] loads landed
    }

    // --- epilogue: out = acc*scale + bias
    const float scale = scale_p[0];
    float bv[4];
#pragma unroll
    for (int ni = 0; ni < 4; ++ni)
        bv[ni] = bias[col0 + wc * 64 + ni * 16 + rl];
#pragma unroll
    for (int mi = 0; mi < 4; ++mi) {
        const int gm0 = row0 + wr * 64 + mi * 16 + lq * 4;
#pragma unroll
        for (int ni = 0; ni < 4; ++ni) {
            const int gn = col0 + wc * 64 + ni * 16 + rl;
#pragma unroll
            for (int j = 0; j < 4; ++j)
                Out[(size_t)(gm0 + j) * 1024 + gn] = acc[mi][ni][j] * scale + bv[ni];
        }
    }
}

// ---------------------------------------------------------------------------
extern "C" void kernel_launch(void* const* d_in, const int* in_sizes, int n_in,
                              void* d_out, int out_size, void* d_ws, size_t ws_size,
                              hipStream_t stream) {
    const float* x    = (const float*)d_in[0];   // [8,8192,1024] fp32
    const float* W    = (const float*)d_in[1];   // [1024,1024]   fp32
    const float* bias = (const float*)d_in[2];   // [1024]        fp32
    float* out = (float*)d_out;

    float*  ws_part  = (float*)d_ws;             // 256 floats
    float*  ws_scale = ws_part + 256;            // 1 float
    bf16_t* ws_T     = (bf16_t*)(ws_part + 512); // 1M bf16 = 2 MB (16B aligned)

    hipLaunchKernelGGL(k_abssum,    dim3(256), dim3(256), 0, stream, W, ws_part);
    hipLaunchKernelGGL(k_ternarize, dim3(512), dim3(256), 0, stream, W, ws_part, ws_T, ws_scale);
    hipLaunchKernelGGL(k_gemm,      dim3(4096), dim3(256), 0, stream, x, ws_T, bias, ws_scale, out);
}